// Round 1
// baseline (141.601 us; speedup 1.0000x reference)
//
#include <hip/hip_runtime.h>
#include <math.h>

#define B_ 16
#define N_ 1024
#define K_ 64
#define C_ 128
#define INV_T 14.285714285714286f  // 1/0.07
#define NBLK_MAIN 1024             // 16 rows per block (4 waves x 4 rows)

__device__ __forceinline__ float waveReduceSum(float v) {
#pragma unroll
    for (int off = 32; off > 0; off >>= 1)
        v += __shfl_xor(v, off, 64);
    return v;
}

__device__ __forceinline__ float waveReduceMax(float v) {
#pragma unroll
    for (int off = 32; off > 0; off >>= 1)
        v = fmaxf(v, __shfl_xor(v, off, 64));
    return v;
}

// Kernel 1: inverse L2 norm of each k row. 16384 rows, wave per row, 4 rows/wave.
__global__ __launch_bounds__(256) void knorm_kernel(const float* __restrict__ k,
                                                    float* __restrict__ inv_k) {
    const int lane = threadIdx.x & 63;
    const int wid  = threadIdx.x >> 6;
    const int base = blockIdx.x * 16 + wid * 4;
#pragma unroll
    for (int r = 0; r < 4; ++r) {
        const int row = base + r;
        const float2 kv = *(const float2*)(k + (size_t)row * C_ + 2 * lane);
        float ss = waveReduceSum(kv.x * kv.x + kv.y * kv.y);
        if (lane == 0) inv_k[row] = 1.0f / fmaxf(sqrtf(ss), 1e-12f);
    }
}

// Kernel 2: per q-row InfoNCE. One wave per row, 4 rows per wave sequentially.
// Lane j owns negative j (K=64 == wave size).
__global__ __launch_bounds__(256) void infonce_kernel(
    const float* __restrict__ q, const float* __restrict__ k,
    const int* __restrict__ pos_idx, const int* __restrict__ neg_idx,
    const float* __restrict__ inv_k, float* __restrict__ partials) {
    __shared__ float q_lds[4][C_];
    __shared__ float wave_tot[4], wave_cnt[4];

    const int lane = threadIdx.x & 63;
    const int wid  = threadIdx.x >> 6;
    const int base = blockIdx.x * 16 + wid * 4;

    float tot = 0.0f, cnt = 0.0f;

    for (int r = 0; r < 4; ++r) {
        const int row = base + r;       // row = b*N + n
        const int b   = row >> 10;      // N_ = 1024

        // Stage raw q row in LDS; compute inv q-norm by wave reduction.
        const float* qrow = q + (size_t)row * C_;
        const float2 qv = *(const float2*)(qrow + 2 * lane);
        *(float2*)(&q_lds[wid][2 * lane]) = qv;
        const float ssq   = waveReduceSum(qv.x * qv.x + qv.y * qv.y);
        const float inv_q = 1.0f / fmaxf(sqrtf(ssq), 1e-12f);

        const float* kb    = k + (size_t)b * (N_ * C_);
        const float* invkb = inv_k + b * N_;

        // Positive: cooperative (coalesced) dot.
        const int pidx   = pos_idx[row];
        const bool pval  = pidx >= 0;
        const int p0     = pval ? pidx : 0;
        const float2 pk  = *(const float2*)(kb + (size_t)p0 * C_ + 2 * lane);
        const float pd   = waveReduceSum(qv.x * pk.x + qv.y * pk.y);
        const float pos_sim = pd * inv_q * invkb[p0] * INV_T;

        __syncthreads();  // q_lds visible (uniform control flow)

        // Negative j for lane j: per-lane dot of length 128 (cache-served rows).
        const int nidx  = neg_idx[(size_t)row * K_ + lane];
        const bool nval = nidx >= 0;
        const int n0    = nval ? nidx : 0;
        const float* krow = kb + (size_t)n0 * C_;
        float dot = 0.0f;
#pragma unroll 8
        for (int c = 0; c < C_; c += 4) {
            const float4 kv4 = *(const float4*)(krow + c);
            const float4 qv4 = *(const float4*)(&q_lds[wid][c]);  // LDS broadcast
            dot = fmaf(kv4.x, qv4.x, dot);
            dot = fmaf(kv4.y, qv4.y, dot);
            dot = fmaf(kv4.z, qv4.z, dot);
            dot = fmaf(kv4.w, qv4.w, dot);
        }
        const float neg_sim = nval ? dot * inv_q * invkb[n0] * INV_T : -INFINITY;

        // logsumexp over [pos, negs]
        const float m = fmaxf(pos_sim, waveReduceMax(neg_sim));
        const float s = waveReduceSum(nval ? __expf(neg_sim - m) : 0.0f)
                        + __expf(pos_sim - m);
        const float per_patch = m + __logf(s) - pos_sim;

        if (pval) { tot += per_patch; cnt += 1.0f; }
        __syncthreads();  // before next iteration's q_lds overwrite
    }

    // Per-wave values are uniform post-reduction; lane 0 holds the wave partial.
    if (lane == 0) { wave_tot[wid] = tot; wave_cnt[wid] = cnt; }
    __syncthreads();
    if (threadIdx.x == 0) {
        partials[2 * blockIdx.x]     = wave_tot[0] + wave_tot[1] + wave_tot[2] + wave_tot[3];
        partials[2 * blockIdx.x + 1] = wave_cnt[0] + wave_cnt[1] + wave_cnt[2] + wave_cnt[3];
    }
}

// Kernel 3: reduce 1024 block partials, emit total / count.
__global__ __launch_bounds__(256) void finalize_kernel(const float* __restrict__ partials,
                                                       float* __restrict__ out, int nblocks) {
    __shared__ float st[256], sc[256];
    float t = 0.0f, c = 0.0f;
    for (int i = threadIdx.x; i < nblocks; i += 256) {
        t += partials[2 * i];
        c += partials[2 * i + 1];
    }
    st[threadIdx.x] = t;
    sc[threadIdx.x] = c;
    __syncthreads();
    for (int off = 128; off > 0; off >>= 1) {
        if (threadIdx.x < off) {
            st[threadIdx.x] += st[threadIdx.x + off];
            sc[threadIdx.x] += sc[threadIdx.x + off];
        }
        __syncthreads();
    }
    if (threadIdx.x == 0) {
        const float cntv = sc[0];
        out[0] = (cntv > 0.0f) ? st[0] / fmaxf(cntv, 1.0f) : 0.0f;
    }
}

extern "C" void kernel_launch(void* const* d_in, const int* in_sizes, int n_in,
                              void* d_out, int out_size, void* d_ws, size_t ws_size,
                              hipStream_t stream) {
    const float* q   = (const float*)d_in[0];
    const float* k   = (const float*)d_in[1];
    const int*   pos = (const int*)d_in[2];
    const int*   neg = (const int*)d_in[3];
    float* out = (float*)d_out;
    float* ws  = (float*)d_ws;

    float* partials = ws;            // 2 * NBLK_MAIN floats
    float* inv_k    = ws + 2048;     // B*N = 16384 floats

    knorm_kernel<<<1024, 256, 0, stream>>>(k, inv_k);
    infonce_kernel<<<NBLK_MAIN, 256, 0, stream>>>(q, k, pos, neg, inv_k, partials);
    finalize_kernel<<<1, 256, 0, stream>>>(partials, out, NBLK_MAIN);
}

// Round 2
// 99.990 us; speedup vs baseline: 1.4162x; 1.4162x over previous
//
#include <hip/hip_runtime.h>
#include <math.h>

#define B_ 16
#define N_ 1024
#define K_ 64
#define C_ 128
#define INV_T 14.285714285714286f  // 1/0.07
#define NBLK_MAIN 1024             // 16 rows per block (4 waves x 4 rows)

__device__ __forceinline__ float waveReduceSum(float v) {
#pragma unroll
    for (int off = 32; off > 0; off >>= 1)
        v += __shfl_xor(v, off, 64);
    return v;
}

__device__ __forceinline__ float waveReduceMax(float v) {
#pragma unroll
    for (int off = 32; off > 0; off >>= 1)
        v = fmaxf(v, __shfl_xor(v, off, 64));
    return v;
}

// One wave per q-row, 4 rows per wave. Negatives gathered cooperatively:
// 8 lanes per k-row (lane = 8*g + s; sub-lane s reads float4 at byte s*16+i*128),
// so every global load instruction covers exactly 8 full 128B lines, once each
// -> no L1-reuse dependence, no traffic amplification. K-norms computed
// in-flight from the same loads (no precompute kernel).
// batch = blockIdx & 15 so XCD (blockIdx % 8) only ever touches 2 of the 16
// 512KB k-slices -> L2-resident gather set, minimal cross-XCD duplication.
__global__ __launch_bounds__(256) void infonce_kernel(
    const float* __restrict__ q, const float* __restrict__ k,
    const int* __restrict__ pos_idx, const int* __restrict__ neg_idx,
    float* __restrict__ partials) {
    __shared__ float q_lds[4][C_];
    __shared__ float wave_tot[4], wave_cnt[4];

    const int lane = threadIdx.x & 63;
    const int wid  = threadIdx.x >> 6;
    const int g    = lane >> 3;   // group 0..7 (one gathered row per group)
    const int s    = lane & 7;    // sub-lane within group

    const int batch = blockIdx.x & 15;   // XCD-affine batch mapping
    const int chunk = blockIdx.x >> 4;
    const int rbase = chunk * 16 + wid * 4;  // row within batch

    const float* kb = k + (size_t)batch * (N_ * C_);

    float tot = 0.0f, cnt = 0.0f;

    for (int r = 0; r < 4; ++r) {
        const int n   = rbase + r;
        const int row = batch * N_ + n;   // global row

        // Stage raw q row in LDS (float2 per lane, coalesced).
        const float* qrow = q + (size_t)row * C_;
        const float2 qv = *(const float2*)(qrow + 2 * lane);
        *(float2*)(&q_lds[wid][2 * lane]) = qv;

        // Positive row (cooperative, coalesced) + q/pos norms, fused reduce.
        const int  pidx = pos_idx[row];
        const bool pval = pidx >= 0;
        const int  p0   = pval ? pidx : 0;
        const float2 pk = *(const float2*)(kb + (size_t)p0 * C_ + 2 * lane);
        float qss = qv.x * qv.x + qv.y * qv.y;
        float pd  = qv.x * pk.x + qv.y * pk.y;
        float pss = pk.x * pk.x + pk.y * pk.y;
#pragma unroll
        for (int off = 32; off > 0; off >>= 1) {
            qss += __shfl_xor(qss, off, 64);
            pd  += __shfl_xor(pd,  off, 64);
            pss += __shfl_xor(pss, off, 64);
        }
        const float inv_q   = 1.0f / fmaxf(sqrtf(qss), 1e-12f);
        const float pos_sim = pd * inv_q / fmaxf(sqrtf(pss), 1e-12f) * INV_T;

        // My negative index (coalesced); broadcast to groups via shfl later.
        const int my_nidx = neg_idx[(size_t)row * K_ + lane];

        __syncthreads();  // q_lds visible (uniform control flow)

        // Each lane's 16 q elements for the group-cooperative dot.
        float4 q4[4];
#pragma unroll
        for (int i = 0; i < 4; ++i)
            q4[i] = *(const float4*)(&q_lds[wid][i * 32 + s * 4]);

        float simv[8];
#pragma unroll
        for (int p = 0; p < 8; ++p) {
            const int  nidx = __shfl(my_nidx, p * 8 + g, 64);
            const bool nval = nidx >= 0;
            const float* kr = kb + (size_t)(nval ? nidx : 0) * C_;
            float dot = 0.0f, kss = 0.0f;
#pragma unroll
            for (int i = 0; i < 4; ++i) {
                const float4 kv = *(const float4*)(kr + i * 32 + s * 4);
                dot = fmaf(kv.x, q4[i].x, dot);
                dot = fmaf(kv.y, q4[i].y, dot);
                dot = fmaf(kv.z, q4[i].z, dot);
                dot = fmaf(kv.w, q4[i].w, dot);
                kss = fmaf(kv.x, kv.x, kss);
                kss = fmaf(kv.y, kv.y, kss);
                kss = fmaf(kv.z, kv.z, kss);
                kss = fmaf(kv.w, kv.w, kss);
            }
#pragma unroll
            for (int off = 1; off < 8; off <<= 1) {
                dot += __shfl_xor(dot, off, 64);
                kss += __shfl_xor(kss, off, 64);
            }
            simv[p] = nval ? dot * inv_q / fmaxf(sqrtf(kss), 1e-12f) * INV_T
                           : -INFINITY;
        }

        // logsumexp over [pos, 64 negs]. Each sim is duplicated across the 8
        // lanes of its group; only s==0 lanes contribute to the sum.
        float m = pos_sim;
#pragma unroll
        for (int p = 0; p < 8; ++p) m = fmaxf(m, simv[p]);
        m = waveReduceMax(m);
        float ssum = 0.0f;
        if (s == 0) {
#pragma unroll
            for (int p = 0; p < 8; ++p) ssum += __expf(simv[p] - m);
        }
        ssum = waveReduceSum(ssum) + __expf(pos_sim - m);
        const float per_patch = m + __logf(ssum) - pos_sim;

        if (pval) { tot += per_patch; cnt += 1.0f; }
        __syncthreads();  // before next iteration's q_lds overwrite
    }

    if (lane == 0) { wave_tot[wid] = tot; wave_cnt[wid] = cnt; }
    __syncthreads();
    if (threadIdx.x == 0) {
        partials[2 * blockIdx.x]     = wave_tot[0] + wave_tot[1] + wave_tot[2] + wave_tot[3];
        partials[2 * blockIdx.x + 1] = wave_cnt[0] + wave_cnt[1] + wave_cnt[2] + wave_cnt[3];
    }
}

// Reduce 1024 block partials, emit total / count.
__global__ __launch_bounds__(256) void finalize_kernel(const float* __restrict__ partials,
                                                       float* __restrict__ out, int nblocks) {
    __shared__ float st[256], sc[256];
    float t = 0.0f, c = 0.0f;
    for (int i = threadIdx.x; i < nblocks; i += 256) {
        t += partials[2 * i];
        c += partials[2 * i + 1];
    }
    st[threadIdx.x] = t;
    sc[threadIdx.x] = c;
    __syncthreads();
    for (int off = 128; off > 0; off >>= 1) {
        if (threadIdx.x < off) {
            st[threadIdx.x] += st[threadIdx.x + off];
            sc[threadIdx.x] += sc[threadIdx.x + off];
        }
        __syncthreads();
    }
    if (threadIdx.x == 0) {
        const float cntv = sc[0];
        out[0] = (cntv > 0.0f) ? st[0] / fmaxf(cntv, 1.0f) : 0.0f;
    }
}

extern "C" void kernel_launch(void* const* d_in, const int* in_sizes, int n_in,
                              void* d_out, int out_size, void* d_ws, size_t ws_size,
                              hipStream_t stream) {
    const float* q   = (const float*)d_in[0];
    const float* k   = (const float*)d_in[1];
    const int*   pos = (const int*)d_in[2];
    const int*   neg = (const int*)d_in[3];
    float* out = (float*)d_out;
    float* ws  = (float*)d_ws;

    float* partials = ws;  // 2 * NBLK_MAIN floats

    infonce_kernel<<<NBLK_MAIN, 256, 0, stream>>>(q, k, pos, neg, partials);
    finalize_kernel<<<1, 256, 0, stream>>>(partials, out, NBLK_MAIN);
}